// Round 2
// baseline (1071.001 us; speedup 1.0000x reference)
//
#include <hip/hip_runtime.h>

// 3-layer LSTM (T=1024,B=512,F=32,H1=32,H2=8,H3=8) + locked dropout.
// Strategy: one 64-lane wave per batch element (512 blocks). Weights in VGPRs,
// h-state broadcast via LDS float4 reads, dropout masks folded into next
// layer's weights / output store. Sequential over T inside the kernel.

constexpr int T = 1024, B = 512, F = 32;
constexpr int H1 = 32, H2 = 8, H3 = 8;

#if __has_builtin(__builtin_amdgcn_rcpf)
#define RCPF(x) __builtin_amdgcn_rcpf(x)
#else
#define RCPF(x) (1.0f / (x))
#endif
#if __has_builtin(__builtin_amdgcn_exp2f)
#define EXP2F(x) __builtin_amdgcn_exp2f(x)
#else
#define EXP2F(x) exp2f(x)
#endif

#define SIG_CM (-1.4426950408889634f)

// unified activation: sigmoid (cm=-log2e, ka=1, kb=0) or tanh (cm=-2log2e, ka=2, kb=-1)
__device__ __forceinline__ float act_f(float v, float cm, float ka, float kb) {
    return fmaf(ka, RCPF(1.0f + EXP2F(v * cm)), kb);
}
__device__ __forceinline__ float tanh_fast(float v) {
    return fmaf(2.0f, RCPF(1.0f + EXP2F(v * (2.0f * SIG_CM))), -1.0f);
}

// NOTE: macro params renamed (ACC/WARR/VEC) so none collides with float4
// members .x/.y/.z/.w — R1's compile failure was `v.w` expanding the `w` param.
#define FMA4(ACC, WARR, VEC, BASE)                                             \
    ACC = fmaf(WARR[(BASE) + 0], VEC.x, ACC);                                  \
    ACC = fmaf(WARR[(BASE) + 1], VEC.y, ACC);                                  \
    ACC = fmaf(WARR[(BASE) + 2], VEC.z, ACC);                                  \
    ACC = fmaf(WARR[(BASE) + 3], VEC.w, ACC);

__global__ __launch_bounds__(64, 1) void lstm3_kernel(
    const float* __restrict__ x,
    const float* __restrict__ Wih1, const float* __restrict__ Whh1,
    const float* __restrict__ bih1, const float* __restrict__ bhh1,
    const float* __restrict__ Wih2, const float* __restrict__ Whh2,
    const float* __restrict__ bih2, const float* __restrict__ bhh2,
    const float* __restrict__ Wih3, const float* __restrict__ Whh3,
    const float* __restrict__ bih3, const float* __restrict__ bhh3,
    const float* __restrict__ mask1, const float* __restrict__ mask2,
    const float* __restrict__ mask3,
    float* __restrict__ out)
{
    const int lane = threadIdx.x;
    const int b = blockIdx.x;

    __shared__ __align__(16) float sh_x[2][F];
    __shared__ __align__(16) float sh_h1[H1];
    __shared__ __align__(16) float sh_h2[H2];
    __shared__ __align__(16) float sh_h3[H3];

    // ---------------- weight / bias / mask setup (registers) ----------------
    // Layer 1: lane handles gate rows r0=lane (i|f half) and r1=lane+64 (g|o half)
    const int r0 = lane;
    const int r1 = lane + 64;
    float wi1a[F], wh1a[H1], wi1b[F], wh1b[H1];
#pragma unroll
    for (int k = 0; k < F; ++k) {
        wi1a[k] = Wih1[r0 * F + k];
        wi1b[k] = Wih1[r1 * F + k];
    }
#pragma unroll
    for (int k = 0; k < H1; ++k) {
        wh1a[k] = Whh1[r0 * H1 + k];
        wh1b[k] = Whh1[r1 * H1 + k];
    }
    const float bias0 = bih1[r0] + bhh1[r0];
    const float bias1 = bih1[r1] + bhh1[r1];
    // activation constants: row0 is always sigmoid (i or f); row1 is tanh (g) for
    // lanes<32, sigmoid (o) for lanes>=32
    const float cm1b = (lane < 32) ? 2.0f * SIG_CM : SIG_CM;
    const float ka1b = (lane < 32) ? 2.0f : 1.0f;
    const float kb1b = (lane < 32) ? -1.0f : 0.0f;

    // Layer 2: row r2 = lane&31 (lanes 32..63 duplicate rows 0..31 harmlessly).
    // Fold mask1 into Wih2 so layer2 consumes raw h1.
    const int r2 = lane & 31;
    float wi2[H1], wh2[H2];
#pragma unroll
    for (int k = 0; k < H1; ++k) wi2[k] = Wih2[r2 * H1 + k] * mask1[b * H1 + k];
#pragma unroll
    for (int k = 0; k < H2; ++k) wh2[k] = Whh2[r2 * H2 + k];
    const float bias2 = bih2[r2] + bhh2[r2];
    const int sec2 = r2 >> 3;  // 0=i 1=f 2=g 3=o
    const float cm2 = (sec2 == 2) ? 2.0f * SIG_CM : SIG_CM;
    const float ka2 = (sec2 == 2) ? 2.0f : 1.0f;
    const float kb2 = (sec2 == 2) ? -1.0f : 0.0f;

    // Layer 3: fold mask2 into Wih3.
    const int r3 = lane & 31;
    float wi3[H2], wh3[H3];
#pragma unroll
    for (int k = 0; k < H2; ++k) wi3[k] = Wih3[r3 * H2 + k] * mask2[b * H2 + k];
#pragma unroll
    for (int k = 0; k < H3; ++k) wh3[k] = Whh3[r3 * H3 + k];
    const float bias3 = bih3[r3] + bhh3[r3];
    const int sec3 = r3 >> 3;
    const float cm3 = (sec3 == 2) ? 2.0f * SIG_CM : SIG_CM;
    const float ka3 = (sec3 == 2) ? 2.0f : 1.0f;
    const float kb3 = (sec3 == 2) ? -1.0f : 0.0f;

    const float m3 = mask3[b * H3 + (lane & 7)];

    // ---------------- state init ----------------
    float c1 = 0.f, c2 = 0.f, c3 = 0.f;
    if (lane < F) sh_x[0][lane] = x[b * F + lane];   // x at t=0
    if (lane < H1) sh_h1[lane] = 0.f;
    if (lane < H2) sh_h2[lane] = 0.f;
    if (lane < H3) sh_h3[lane] = 0.f;
    __syncthreads();

    const int j = lane & 7;

    for (int t = 0; t < T; ++t) {
        const int cur = t & 1, nxt = cur ^ 1;

        // prefetch next timestep's x slice early (latency hidden behind layer1)
        float xnext = 0.f;
        {
            const int tn = (t + 1 < T) ? (t + 1) : t;
            if (lane < F) xnext = x[tn * (B * F) + b * F + lane];
        }

        // ---------------- layer 1 ----------------
        float a0x = 0.f, a0h = 0.f, a1x = 0.f, a1h = 0.f;
        {
            const float4* xp = (const float4*)sh_x[cur];
            const float4* hp = (const float4*)sh_h1;
#pragma unroll
            for (int q = 0; q < 8; ++q) {
                float4 xv = xp[q];
                float4 hv = hp[q];
                FMA4(a0x, wi1a, xv, 4 * q);
                FMA4(a0h, wh1a, hv, 4 * q);
                FMA4(a1x, wi1b, xv, 4 * q);
                FMA4(a1h, wh1b, hv, 4 * q);
            }
        }
        const float a0 = bias0 + a0x + a0h;
        const float a1 = bias1 + a1x + a1h;
        // lanes<32: g0=i, g1=g ; lanes>=32: g0=f, g1=o
        const float g0 = act_f(a0, SIG_CM, 1.0f, 0.0f);
        const float g1 = act_f(a1, cm1b, ka1b, kb1b);
        const float f_ = __shfl_xor(g0, 32);
        const float o_ = __shfl_xor(g1, 32);
        c1 = fmaf(f_, c1, g0 * g1);                 // meaningful in lanes<32
        const float h1 = o_ * tanh_fast(c1);

        __syncthreads();  // all reads of old sh_h1 / sh_x[cur] complete
        if (lane < H1) sh_h1[lane] = h1;
        if (lane < F) sh_x[nxt][lane] = xnext;
        __syncthreads();  // new h1 (and next x) visible

        // ---------------- layer 2 (input = h1, mask folded) ----------------
        float a2x = 0.f, a2h = 0.f;
        {
            const float4* hp = (const float4*)sh_h1;
#pragma unroll
            for (int q = 0; q < 8; ++q) {
                float4 hv = hp[q];
                FMA4(a2x, wi2, hv, 4 * q);
            }
            const float4* h2p = (const float4*)sh_h2;
            float4 v0 = h2p[0], v1 = h2p[1];
            FMA4(a2h, wh2, v0, 0);
            FMA4(a2h, wh2, v1, 4);
        }
        const float a2 = bias2 + a2x + a2h;
        const float r2v = act_f(a2, cm2, ka2, kb2);
        const float i2 = __shfl(r2v, j);
        const float f2 = __shfl(r2v, j + 8);
        const float g2 = __shfl(r2v, j + 16);
        const float o2 = __shfl(r2v, j + 24);
        c2 = fmaf(f2, c2, i2 * g2);
        const float h2 = o2 * tanh_fast(c2);

        __syncthreads();  // reads of old sh_h2 complete
        if (lane < H2) sh_h2[lane] = h2;
        __syncthreads();  // new h2 visible

        // ---------------- layer 3 (input = h2, mask folded) ----------------
        float a3x = 0.f, a3h = 0.f;
        {
            const float4* h2p = (const float4*)sh_h2;
            const float4* h3p = (const float4*)sh_h3;
            float4 u0 = h2p[0], u1 = h2p[1];
            FMA4(a3x, wi3, u0, 0);
            FMA4(a3x, wi3, u1, 4);
            float4 w0 = h3p[0], w1 = h3p[1];
            FMA4(a3h, wh3, w0, 0);
            FMA4(a3h, wh3, w1, 4);
        }
        const float a3 = bias3 + a3x + a3h;
        const float r3v = act_f(a3, cm3, ka3, kb3);
        const float i3 = __shfl(r3v, j);
        const float f3 = __shfl(r3v, j + 8);
        const float g3 = __shfl(r3v, j + 16);
        const float o3 = __shfl(r3v, j + 24);
        c3 = fmaf(f3, c3, i3 * g3);
        const float h3 = o3 * tanh_fast(c3);

        if (lane < H3) out[t * (B * H3) + b * H3 + lane] = h3 * m3;

        __syncthreads();  // reads of old sh_h3 complete
        if (lane < H3) sh_h3[lane] = h3;
        // visibility for next step's layer-3 read is covered by the next
        // iteration's barriers.
    }
}

extern "C" void kernel_launch(void* const* d_in, const int* in_sizes, int n_in,
                              void* d_out, int out_size, void* d_ws, size_t ws_size,
                              hipStream_t stream) {
    (void)in_sizes; (void)n_in; (void)d_ws; (void)ws_size; (void)out_size;
    const float* x     = (const float*)d_in[0];
    const float* Wih1  = (const float*)d_in[1];
    const float* Whh1  = (const float*)d_in[2];
    const float* bih1  = (const float*)d_in[3];
    const float* bhh1  = (const float*)d_in[4];
    const float* Wih2  = (const float*)d_in[5];
    const float* Whh2  = (const float*)d_in[6];
    const float* bih2  = (const float*)d_in[7];
    const float* bhh2  = (const float*)d_in[8];
    const float* Wih3  = (const float*)d_in[9];
    const float* Whh3  = (const float*)d_in[10];
    const float* bih3  = (const float*)d_in[11];
    const float* bhh3  = (const float*)d_in[12];
    const float* mask1 = (const float*)d_in[13];
    const float* mask2 = (const float*)d_in[14];
    const float* mask3 = (const float*)d_in[15];
    float* out = (float*)d_out;

    lstm3_kernel<<<dim3(B), dim3(64), 0, stream>>>(
        x, Wih1, Whh1, bih1, bhh1, Wih2, Whh2, bih2, bhh2,
        Wih3, Whh3, bih3, bhh3, mask1, mask2, mask3, out);
}

// Round 3
// 1030.596 us; speedup vs baseline: 1.0392x; 1.0392x over previous
//
#include <hip/hip_runtime.h>

// 3-layer LSTM (T=1024,B=512,F=32,H1=32,H2=8,H3=8) + locked dropout.
// One 64-lane wave per batch element (512 blocks). Weights in VGPRs, h-state
// broadcast via LDS float4 reads, dropout masks folded into next layer's
// weights / output store. Sequential over T inside the kernel.
//
// R3 change: blocks are a SINGLE wave, so __syncthreads() (s_waitcnt
// vmcnt(0) lgkmcnt(0) + s_barrier) is replaced by a pure compiler memory
// clobber. HW guarantee used: DS ops from one wave are processed in order,
// and the compiler auto-inserts lgkmcnt waits for read data. This removes
// the 5x/step vmcnt(0) drains that were forcing the out-store and
// x-prefetch onto the critical path.

constexpr int T = 1024, B = 512, F = 32;
constexpr int H1 = 32, H2 = 8, H3 = 8;

// compiler-only memory barrier: orders LDS writes vs reads in the
// instruction stream; zero hardware instructions.
#define WAVE_SYNC() asm volatile("" ::: "memory")

#if __has_builtin(__builtin_amdgcn_rcpf)
#define RCPF(x) __builtin_amdgcn_rcpf(x)
#else
#define RCPF(x) (1.0f / (x))
#endif
#if __has_builtin(__builtin_amdgcn_exp2f)
#define EXP2F(x) __builtin_amdgcn_exp2f(x)
#else
#define EXP2F(x) exp2f(x)
#endif

#define SIG_CM (-1.4426950408889634f)

// unified activation: sigmoid (cm=-log2e, ka=1, kb=0) or tanh (cm=-2log2e, ka=2, kb=-1)
__device__ __forceinline__ float act_f(float v, float cm, float ka, float kb) {
    return fmaf(ka, RCPF(1.0f + EXP2F(v * cm)), kb);
}
__device__ __forceinline__ float tanh_fast(float v) {
    return fmaf(2.0f, RCPF(1.0f + EXP2F(v * (2.0f * SIG_CM))), -1.0f);
}

// macro params avoid float4 member names x/y/z/w (R1 lesson)
#define FMA4(ACC, WARR, VEC, BASE)                                             \
    ACC = fmaf(WARR[(BASE) + 0], VEC.x, ACC);                                  \
    ACC = fmaf(WARR[(BASE) + 1], VEC.y, ACC);                                  \
    ACC = fmaf(WARR[(BASE) + 2], VEC.z, ACC);                                  \
    ACC = fmaf(WARR[(BASE) + 3], VEC.w, ACC);

__global__ __launch_bounds__(64, 1) void lstm3_kernel(
    const float* __restrict__ x,
    const float* __restrict__ Wih1, const float* __restrict__ Whh1,
    const float* __restrict__ bih1, const float* __restrict__ bhh1,
    const float* __restrict__ Wih2, const float* __restrict__ Whh2,
    const float* __restrict__ bih2, const float* __restrict__ bhh2,
    const float* __restrict__ Wih3, const float* __restrict__ Whh3,
    const float* __restrict__ bih3, const float* __restrict__ bhh3,
    const float* __restrict__ mask1, const float* __restrict__ mask2,
    const float* __restrict__ mask3,
    float* __restrict__ out)
{
    const int lane = threadIdx.x;
    const int b = blockIdx.x;

    __shared__ __align__(16) float sh_x[2][F];
    __shared__ __align__(16) float sh_h1[H1];
    __shared__ __align__(16) float sh_h2[H2];
    __shared__ __align__(16) float sh_h3[H3];

    // ---------------- weight / bias / mask setup (registers) ----------------
    const int r0 = lane;
    const int r1 = lane + 64;
    float wi1a[F], wh1a[H1], wi1b[F], wh1b[H1];
#pragma unroll
    for (int k = 0; k < F; ++k) {
        wi1a[k] = Wih1[r0 * F + k];
        wi1b[k] = Wih1[r1 * F + k];
    }
#pragma unroll
    for (int k = 0; k < H1; ++k) {
        wh1a[k] = Whh1[r0 * H1 + k];
        wh1b[k] = Whh1[r1 * H1 + k];
    }
    const float bias0 = bih1[r0] + bhh1[r0];
    const float bias1 = bih1[r1] + bhh1[r1];
    const float cm1b = (lane < 32) ? 2.0f * SIG_CM : SIG_CM;
    const float ka1b = (lane < 32) ? 2.0f : 1.0f;
    const float kb1b = (lane < 32) ? -1.0f : 0.0f;

    const int r2 = lane & 31;
    float wi2[H1], wh2[H2];
#pragma unroll
    for (int k = 0; k < H1; ++k) wi2[k] = Wih2[r2 * H1 + k] * mask1[b * H1 + k];
#pragma unroll
    for (int k = 0; k < H2; ++k) wh2[k] = Whh2[r2 * H2 + k];
    const float bias2 = bih2[r2] + bhh2[r2];
    const int sec2 = r2 >> 3;
    const float cm2 = (sec2 == 2) ? 2.0f * SIG_CM : SIG_CM;
    const float ka2 = (sec2 == 2) ? 2.0f : 1.0f;
    const float kb2 = (sec2 == 2) ? -1.0f : 0.0f;

    const int r3 = lane & 31;
    float wi3[H2], wh3[H3];
#pragma unroll
    for (int k = 0; k < H2; ++k) wi3[k] = Wih3[r3 * H2 + k] * mask2[b * H2 + k];
#pragma unroll
    for (int k = 0; k < H3; ++k) wh3[k] = Whh3[r3 * H3 + k];
    const float bias3 = bih3[r3] + bhh3[r3];
    const int sec3 = r3 >> 3;
    const float cm3 = (sec3 == 2) ? 2.0f * SIG_CM : SIG_CM;
    const float ka3 = (sec3 == 2) ? 2.0f : 1.0f;
    const float kb3 = (sec3 == 2) ? -1.0f : 0.0f;

    const float m3 = mask3[b * H3 + (lane & 7)];

    // ---------------- state init ----------------
    float c1 = 0.f, c2 = 0.f, c3 = 0.f;
    if (lane < F) sh_x[0][lane] = x[b * F + lane];   // x at t=0
    if (lane < H1) sh_h1[lane] = 0.f;
    if (lane < H2) sh_h2[lane] = 0.f;
    if (lane < H3) sh_h3[lane] = 0.f;
    WAVE_SYNC();

    const int j = lane & 7;

    for (int t = 0; t < T; ++t) {
        const int cur = t & 1, nxt = cur ^ 1;

        // prefetch next timestep's x slice (latency hidden behind layer1;
        // no vmcnt(0) drains remain, so this is truly asynchronous now)
        float xnext = 0.f;
        {
            const int tn = (t + 1 < T) ? (t + 1) : t;
            if (lane < F) xnext = x[tn * (B * F) + b * F + lane];
        }

        // ---------------- layer 1 ----------------
        float a0x = 0.f, a0h = 0.f, a1x = 0.f, a1h = 0.f;
        {
            const float4* xp = (const float4*)sh_x[cur];
            const float4* hp = (const float4*)sh_h1;
#pragma unroll
            for (int q = 0; q < 8; ++q) {
                float4 xv = xp[q];
                float4 hv = hp[q];
                FMA4(a0x, wi1a, xv, 4 * q);
                FMA4(a0h, wh1a, hv, 4 * q);
                FMA4(a1x, wi1b, xv, 4 * q);
                FMA4(a1h, wh1b, hv, 4 * q);
            }
        }
        const float a0 = bias0 + a0x + a0h;
        const float a1 = bias1 + a1x + a1h;
        const float g0 = act_f(a0, SIG_CM, 1.0f, 0.0f);
        const float g1 = act_f(a1, cm1b, ka1b, kb1b);
        const float f_ = __shfl_xor(g0, 32);
        const float o_ = __shfl_xor(g1, 32);
        c1 = fmaf(f_, c1, g0 * g1);
        const float h1 = o_ * tanh_fast(c1);

        WAVE_SYNC();  // reads of old sh_h1 / sh_x[cur] are ordered before...
        if (lane < H1) sh_h1[lane] = h1;
        if (lane < F) sh_x[nxt][lane] = xnext;
        WAVE_SYNC();  // ...and the writes before the reads below

        // ---------------- layer 2 (input = h1, mask folded) ----------------
        float a2x = 0.f, a2h = 0.f;
        {
            const float4* hp = (const float4*)sh_h1;
#pragma unroll
            for (int q = 0; q < 8; ++q) {
                float4 hv = hp[q];
                FMA4(a2x, wi2, hv, 4 * q);
            }
            const float4* h2p = (const float4*)sh_h2;
            float4 v0 = h2p[0], v1 = h2p[1];
            FMA4(a2h, wh2, v0, 0);
            FMA4(a2h, wh2, v1, 4);
        }
        const float a2 = bias2 + a2x + a2h;
        const float r2v = act_f(a2, cm2, ka2, kb2);
        const float i2 = __shfl(r2v, j);
        const float f2 = __shfl(r2v, j + 8);
        const float g2 = __shfl(r2v, j + 16);
        const float o2 = __shfl(r2v, j + 24);
        c2 = fmaf(f2, c2, i2 * g2);
        const float h2 = o2 * tanh_fast(c2);

        WAVE_SYNC();
        if (lane < H2) sh_h2[lane] = h2;
        WAVE_SYNC();

        // ---------------- layer 3 (input = h2, mask folded) ----------------
        float a3x = 0.f, a3h = 0.f;
        {
            const float4* h2p = (const float4*)sh_h2;
            const float4* h3p = (const float4*)sh_h3;
            float4 u0 = h2p[0], u1 = h2p[1];
            FMA4(a3x, wi3, u0, 0);
            FMA4(a3x, wi3, u1, 4);
            float4 w0 = h3p[0], w1 = h3p[1];
            FMA4(a3h, wh3, w0, 0);
            FMA4(a3h, wh3, w1, 4);
        }
        const float a3 = bias3 + a3x + a3h;
        const float r3v = act_f(a3, cm3, ka3, kb3);
        const float i3 = __shfl(r3v, j);
        const float f3 = __shfl(r3v, j + 8);
        const float g3 = __shfl(r3v, j + 16);
        const float o3 = __shfl(r3v, j + 24);
        c3 = fmaf(f3, c3, i3 * g3);
        const float h3 = o3 * tanh_fast(c3);

        if (lane < H3) out[t * (B * H3) + b * H3 + lane] = h3 * m3;

        WAVE_SYNC();
        if (lane < H3) sh_h3[lane] = h3;
        WAVE_SYNC();
    }
}

extern "C" void kernel_launch(void* const* d_in, const int* in_sizes, int n_in,
                              void* d_out, int out_size, void* d_ws, size_t ws_size,
                              hipStream_t stream) {
    (void)in_sizes; (void)n_in; (void)d_ws; (void)ws_size; (void)out_size;
    const float* x     = (const float*)d_in[0];
    const float* Wih1  = (const float*)d_in[1];
    const float* Whh1  = (const float*)d_in[2];
    const float* bih1  = (const float*)d_in[3];
    const float* bhh1  = (const float*)d_in[4];
    const float* Wih2  = (const float*)d_in[5];
    const float* Whh2  = (const float*)d_in[6];
    const float* bih2  = (const float*)d_in[7];
    const float* bhh2  = (const float*)d_in[8];
    const float* Wih3  = (const float*)d_in[9];
    const float* Whh3  = (const float*)d_in[10];
    const float* bih3  = (const float*)d_in[11];
    const float* bhh3  = (const float*)d_in[12];
    const float* mask1 = (const float*)d_in[13];
    const float* mask2 = (const float*)d_in[14];
    const float* mask3 = (const float*)d_in[15];
    float* out = (float*)d_out;

    lstm3_kernel<<<dim3(B), dim3(64), 0, stream>>>(
        x, Wih1, Whh1, bih1, bhh1, Wih2, Whh2, bih2, bhh2,
        Wih3, Whh3, bih3, bhh3, mask1, mask2, mask3, out);
}